// Round 18
// baseline (512.735 us; speedup 1.0000x reference)
//
#include <hip/hip_runtime.h>
#include <math.h>

// MultiomicTransformer on MI355X — Round 18: flash processes 2 kv-chunks per barrier iteration
// (halves barrier + reduce overhead; P reuse keeps LDS at 40 KB). Rest identical to R17.
// B=8 W=2048 WIN=1024 D=512 NH=8 HD=64 DFF=2048 L=4 KS=4 G=2048 S=512

typedef __attribute__((ext_vector_type(8))) short short8v;
typedef __attribute__((ext_vector_type(4))) float float4v;
typedef const __attribute__((address_space(1))) void* gas_t;
typedef __attribute__((address_space(3))) void* las_t;

__device__ inline unsigned short f2bf(float f) {
    unsigned int u = __builtin_bit_cast(unsigned int, f);
    return (unsigned short)((u + 0x7fffu + ((u >> 16) & 1u)) >> 16);   // RNE
}

__device__ inline unsigned cvt_pk_bf16(float lo, float hi) {          // [bf16(lo) | bf16(hi)<<16]
    unsigned r;
    asm("v_cvt_pk_bf16_f32 %0, %1, %2" : "=v"(r) : "v"(lo), "v"(hi));
    return r;
}

// ---------------------------------------------------------------- all-weights fp32 -> bf16 (single launch)
__global__ __launch_bounds__(256) void cvt_all_k(
    const float* __restrict__ s0, const float* __restrict__ s1, const float* __restrict__ s2,
    const float* __restrict__ s3, const float* __restrict__ s4, const float* __restrict__ s5,
    const float* __restrict__ s6, unsigned short* __restrict__ dst)
{
    constexpr int c1 = 131072, c2 = 917504, c3 = 1179648, c4 = 2228224, c5 = 3276800, c6 = 3473408;
    int i = blockIdx.x * 256 + threadIdx.x;            // grid exactly covers 3538944 float4s
    const float* s = s0; int base = 0;
    if (i >= c1) { s = s1; base = c1; }
    if (i >= c2) { s = s2; base = c2; }
    if (i >= c3) { s = s3; base = c3; }
    if (i >= c4) { s = s4; base = c4; }
    if (i >= c5) { s = s5; base = c5; }
    if (i >= c6) { s = s6; base = c6; }
    float4 v = ((const float4*)s)[i - base];
    ushort4 o;
    o.x = f2bf(v.x); o.y = f2bf(v.y); o.z = f2bf(v.z); o.w = f2bf(v.w);
    ((ushort4*)dst)[i] = o;
}

// ---------------------------------------------------------------- pool mean-4 (commutes with win-proj), bf16 out
__global__ __launch_bounds__(256) void pool_windows_k(const float* __restrict__ win,
                                                      unsigned short* __restrict__ pw)
{
    int idx = blockIdx.x * 256 + threadIdx.x;
    int n = idx >> 8, c4 = (idx & 255) << 2;
    const float* base = win + (size_t)n * 4096 + c4;
    float4 a = *(const float4*)(base);
    float4 b2 = *(const float4*)(base + 1024);
    float4 c = *(const float4*)(base + 2048);
    float4 d = *(const float4*)(base + 3072);
    ushort4 r;
    r.x = f2bf((a.x + b2.x + c.x + d.x) * 0.25f);
    r.y = f2bf((a.y + b2.y + c.y + d.y) * 0.25f);
    r.z = f2bf((a.z + b2.z + c.z + d.z) * 0.25f);
    r.w = f2bf((a.w + b2.w + c.w + d.w) * 0.25f);
    ((ushort4*)pw)[idx] = r;
}

// ---------------------------------------------------------------- bf16 MFMA GEMM (double-buffer, counted vmcnt)
template<int BM, int BN, bool BIAS, bool BROW, bool RES, bool RELU, bool POSENC, bool O32, bool O16>
__global__ __launch_bounds__(256) void gemm_bf16_k(
    const unsigned short* __restrict__ A, const unsigned short* __restrict__ Bw,
    const float* __restrict__ bias, const float* __restrict__ Res,
    float* __restrict__ C32, unsigned short* __restrict__ C16,
    int M, int N, int K)
{
    constexpr int BK   = (BM == 128) ? 32 : 64;
    constexpr int CPR  = BK / 8;
    constexpr int WR   = (BM == 64 && BN == 128) ? 1 : 2;
    constexpr int WC   = 4 / WR;
    constexpr int MSTEP = BM / WR;
    constexpr int NSTEP = BN / WC;
    constexpr int MFR  = MSTEP / 16;
    constexpr int NFR  = NSTEP / 16;
    constexpr int LPTA = BM * BK / 2048;
    constexpr int LPTB = BN * BK / 2048;
    constexpr int LPT  = LPTA + LPTB;            // 4 or 6
    __shared__ __align__(16) unsigned short As[2][BM * BK];
    __shared__ __align__(16) unsigned short Bs[2][BN * BK];
    const int tid = threadIdx.x;
    const int lane = tid & 63;
    const int m0 = blockIdx.x * BM, n0 = blockIdx.y * BN;
    const int wid = tid >> 6;
    const int wr = wid / WC, wc = wid % WC;
    const int r = lane & 15, g = lane >> 4;

    const unsigned short* gA[LPTA];
    const unsigned short* gB[LPTB];
    #pragma unroll
    for (int j = 0; j < LPTA; ++j) {
        int c = tid + j * 256, row = c / CPR, cc = c % CPR;
        gA[j] = A + (size_t)(m0 + row) * K + ((cc ^ (row & (CPR - 1))) * 8);
    }
    #pragma unroll
    for (int j = 0; j < LPTB; ++j) {
        int c = tid + j * 256, row = c / CPR, cc = c % CPR;
        gB[j] = Bw + (size_t)(n0 + row) * K + ((cc ^ (row & (CPR - 1))) * 8);
    }

    auto stage = [&](int bi, int k0) {
        #pragma unroll
        for (int j = 0; j < LPTA; ++j)
            __builtin_amdgcn_global_load_lds((gas_t)(gA[j] + k0), (las_t)(&As[bi][(tid + j * 256) * 8]), 16, 0, 0);
        #pragma unroll
        for (int j = 0; j < LPTB; ++j)
            __builtin_amdgcn_global_load_lds((gas_t)(gB[j] + k0), (las_t)(&Bs[bi][(tid + j * 256) * 8]), 16, 0, 0);
    };

    float4v acc[MFR][NFR];
    float4v z4 = {0.f, 0.f, 0.f, 0.f};
    #pragma unroll
    for (int i = 0; i < MFR; ++i)
        #pragma unroll
        for (int j = 0; j < NFR; ++j) acc[i][j] = z4;

    stage(0, 0);
    int buf = 0;
    for (int k0 = 0; k0 < K; k0 += BK) {
        if (k0 + BK < K) {
            stage(buf ^ 1, k0 + BK);                      // prefetch: stays in flight across barrier
            if constexpr (LPT == 4) asm volatile("s_waitcnt vmcnt(4)" ::: "memory");
            else                    asm volatile("s_waitcnt vmcnt(6)" ::: "memory");
        } else {
            asm volatile("s_waitcnt vmcnt(0)" ::: "memory");
        }
        __builtin_amdgcn_sched_barrier(0);
        __builtin_amdgcn_s_barrier();                     // raw: no compiler drain
        __builtin_amdgcn_sched_barrier(0);
        #pragma unroll
        for (int kk = 0; kk < BK / 32; ++kk) {
            const int cx = ((kk * 4 + g) ^ (r & (CPR - 1))) * 8;
            short8v a[MFR], b[NFR];
            #pragma unroll
            for (int mi = 0; mi < MFR; ++mi)
                a[mi] = *(const short8v*)&As[buf][(MSTEP * wr + 16 * mi + r) * BK + cx];
            #pragma unroll
            for (int ni = 0; ni < NFR; ++ni)
                b[ni] = *(const short8v*)&Bs[buf][(NSTEP * wc + 16 * ni + r) * BK + cx];
            #pragma unroll
            for (int mi = 0; mi < MFR; ++mi)
                #pragma unroll
                for (int ni = 0; ni < NFR; ++ni)
                    acc[mi][ni] = __builtin_amdgcn_mfma_f32_16x16x32_bf16(a[mi], b[ni], acc[mi][ni], 0, 0, 0);
        }
        __builtin_amdgcn_sched_barrier(0);
        __builtin_amdgcn_s_barrier();                     // skew bound: reads of buf done before reuse
        buf ^= 1;
    }

    #pragma unroll
    for (int mi = 0; mi < MFR; ++mi) {
        #pragma unroll
        for (int ni = 0; ni < NFR; ++ni) {
            const int row0 = m0 + MSTEP * wr + 16 * mi + g * 4;
            const int col  = n0 + NSTEP * wc + 16 * ni + r;
            float bv = (BIAS && !BROW) ? bias[col] : 0.f;
            float fr = 0.f;
            if (POSENC) fr = __expf((float)(col & ~1) * -0.01798894600f);
            #pragma unroll
            for (int q = 0; q < 4; ++q) {
                const int row = row0 + q;
                float v = acc[mi][ni][q] + bv;
                if (BIAS && BROW) v += bias[row];
                if (POSENC) {
                    float ang = (float)(row & 511) * fr;
                    v += (col & 1) ? __cosf(ang) : __sinf(ang);
                }
                if (RES) v += Res[(size_t)row * N + col];
                if (RELU) v = fmaxf(v, 0.0f);
                if (O32) C32[(size_t)row * N + col] = v;
                if (O16) C16[(size_t)row * N + col] = f2bf(v);
            }
        }
    }
}

// ---------------------------------------------------------------- flash attention: 2 kv-chunks per barrier iteration
// grid: x = h + 8*b (XCD colocation), y = qt, z = split. nc must be EVEN.
// Per iteration: stage both chunks -> sync -> QK over 128 kv -> one softmax
// reduce -> (P write + PV) per half (P rows wave-private, no inner barrier) -> sync.
template<bool SPLIT>
__global__ __launch_bounds__(256) void flashc_k(
    const unsigned short* __restrict__ Qp, long long q_bs, int q_rs,
    const unsigned short* __restrict__ Kp, long long k_bs, int k_rs,
    const unsigned short* __restrict__ Vtp, long long v_hs, long long v_bs, int v_rs,
    unsigned short* __restrict__ Op, long long o_bs, int o_rs,
    unsigned short* __restrict__ opart, long long part_stride, int q_rows,
    float2* __restrict__ Ml, int nc)
{
    constexpr float C1 = 0.18033688011112042f;   // 0.125 * log2(e)
    __shared__ __align__(16) unsigned short Kb[2][64 * 64];
    __shared__ __align__(16) unsigned short Vb[2][64 * 64];
    __shared__ __align__(16) unsigned short Ps[64 * 64];
    const int hb = blockIdx.x, qt = blockIdx.y, s = blockIdx.z;
    const int h = hb & 7, b = hb >> 3;
    const unsigned short* Q  = Qp  + (size_t)b * q_bs + (size_t)h * 64;
    const unsigned short* Kg = Kp  + (size_t)b * k_bs + (size_t)h * 64 + (size_t)(s * nc * 64) * k_rs;
    const unsigned short* Vg = Vtp + (size_t)h * v_hs + (size_t)b * v_bs + (size_t)(s * nc) * 64;
    const int q0 = qt * 64;
    const int tid = threadIdx.x, lane = tid & 63, w = tid >> 6;
    const int r = lane & 15, g = lane >> 4;
    const int sw8 = (r & 7) * 8;
    const int cA = (g * 8) ^ sw8;
    const int cB = ((g + 4) * 8) ^ sw8;
    const int prow = (16 * w + r) * 64;

    const unsigned short* qrow = Q + (size_t)(q0 + 16 * w + r) * q_rs + g * 8;
    short8v qf0 = *(const short8v*)(qrow);
    short8v qf1 = *(const short8v*)(qrow + 32);

    const int r0 = tid >> 3, cc = tid & 7;
    const int srcc = (cc ^ (r0 & 7)) * 8;
    auto stage1 = [&](int half, int c) {     // chunk c -> Kb[half]/Vb[half]
        const unsigned short* kc_ = Kg + (size_t)c * 64 * k_rs;
        const unsigned short* vc_ = Vg + (size_t)c * 64;
        __builtin_amdgcn_global_load_lds((gas_t)(kc_ + (size_t)r0 * k_rs + srcc),
                                         (las_t)(&Kb[half][tid * 8]), 16, 0, 0);
        __builtin_amdgcn_global_load_lds((gas_t)(kc_ + (size_t)(r0 + 32) * k_rs + srcc),
                                         (las_t)(&Kb[half][(tid + 256) * 8]), 16, 0, 0);
        __builtin_amdgcn_global_load_lds((gas_t)(vc_ + (size_t)r0 * v_rs + srcc),
                                         (las_t)(&Vb[half][tid * 8]), 16, 0, 0);
        __builtin_amdgcn_global_load_lds((gas_t)(vc_ + (size_t)(r0 + 32) * v_rs + srcc),
                                         (las_t)(&Vb[half][(tid + 256) * 8]), 16, 0, 0);
    };

    float4v acc_o[4];
    float4v z4 = {0.f, 0.f, 0.f, 0.f};
    #pragma unroll
    for (int dt = 0; dt < 4; ++dt) acc_o[dt] = z4;
    float m_own = -INFINITY, l_own = 0.f;

    for (int c = 0; c < nc; c += 2) {
        stage1(0, c);
        stage1(1, c + 1);
        __syncthreads();                       // drains loads; K/V visible to all waves

        // QK^T over both chunks (128 kv): lane holds S[q=r][kv = half*64 + 16t + g*4 + reg]
        __builtin_amdgcn_s_setprio(1);
        float4v accs[8];
        #pragma unroll
        for (int half = 0; half < 2; ++half)
            #pragma unroll
            for (int t = 0; t < 4; ++t) {
                float4v a = z4;
                const unsigned short* krow = Kb[half] + (16 * t + r) * 64;
                short8v kf0 = *(const short8v*)(krow + cA);
                short8v kf1 = *(const short8v*)(krow + cB);
                a = __builtin_amdgcn_mfma_f32_16x16x32_bf16(kf0, qf0, a, 0, 0, 0);
                a = __builtin_amdgcn_mfma_f32_16x16x32_bf16(kf1, qf1, a, 0, 0, 0);
                accs[half * 4 + t] = a;
            }
        __builtin_amdgcn_s_setprio(0);

        // one softmax reduce over 32 values
        float sm = accs[0][0];
        #pragma unroll
        for (int t = 0; t < 8; ++t)
            #pragma unroll
            for (int j = 0; j < 4; ++j) sm = fmaxf(sm, accs[t][j]);
        sm = fmaxf(sm, __shfl_xor(sm, 16));
        sm = fmaxf(sm, __shfl_xor(sm, 32));

        if (__any(sm > m_own + 64.f)) {
            float mn = fmaxf(m_own, sm);
            float alpha = __builtin_amdgcn_exp2f((m_own - mn) * C1);   // first iter: 0
            m_own = mn;
            float a0_ = __shfl(alpha, g * 4 + 0);
            float a1_ = __shfl(alpha, g * 4 + 1);
            float a2_ = __shfl(alpha, g * 4 + 2);
            float a3_ = __shfl(alpha, g * 4 + 3);
            #pragma unroll
            for (int dt = 0; dt < 4; ++dt) {
                acc_o[dt][0] *= a0_; acc_o[dt][1] *= a1_;
                acc_o[dt][2] *= a2_; acc_o[dt][3] *= a3_;
            }
            l_own *= alpha;
        }

        const float m2c = m_own * C1;
        float p[8][4];
        float rsum = 0.f;
        #pragma unroll
        for (int t = 0; t < 8; ++t)
            #pragma unroll
            for (int j = 0; j < 4; ++j) {
                float pv = __builtin_amdgcn_exp2f(__builtin_fmaf(accs[t][j], C1, -m2c));
                p[t][j] = pv; rsum += pv;
            }
        rsum += __shfl_xor(rsum, 16);
        rsum += __shfl_xor(rsum, 32);
        l_own += rsum;

        // per half: P write (wave-private rows; intra-wave ds dependency only) then PV
        #pragma unroll
        for (int half = 0; half < 2; ++half) {
            #pragma unroll
            for (int t = 0; t < 4; ++t) {
                uint2 uu;
                uu.x = cvt_pk_bf16(p[half * 4 + t][0], p[half * 4 + t][1]);
                uu.y = cvt_pk_bf16(p[half * 4 + t][2], p[half * 4 + t][3]);
                int pc = (((2 * t + (g >> 1)) * 8) ^ sw8) + (g & 1) * 4;
                *(uint2*)&Ps[prow + pc] = uu;
            }
            __builtin_amdgcn_s_setprio(1);
            short8v pf0 = *(const short8v*)&Ps[prow + cA];
            short8v pf1 = *(const short8v*)&Ps[prow + cB];
            #pragma unroll
            for (int dt = 0; dt < 4; ++dt) {
                const unsigned short* vrow = Vb[half] + (16 * dt + r) * 64;
                short8v vf0 = *(const short8v*)(vrow + cA);
                short8v vf1 = *(const short8v*)(vrow + cB);
                acc_o[dt] = __builtin_amdgcn_mfma_f32_16x16x32_bf16(pf0, vf0, acc_o[dt], 0, 0, 0);
                acc_o[dt] = __builtin_amdgcn_mfma_f32_16x16x32_bf16(pf1, vf1, acc_o[dt], 0, 0, 0);
            }
            __builtin_amdgcn_s_setprio(0);
        }

        __syncthreads();                       // all waves done reading K/V before next stage
    }

    float il0 = 1.f / __shfl(l_own, g * 4 + 0);
    float il1 = 1.f / __shfl(l_own, g * 4 + 1);
    float il2 = 1.f / __shfl(l_own, g * 4 + 2);
    float il3 = 1.f / __shfl(l_own, g * 4 + 3);
    if (SPLIT) {
        unsigned short* Ob = opart + (size_t)s * part_stride
                           + ((size_t)(b * q_rows)) * 512 + h * 64;
        #pragma unroll
        for (int dt = 0; dt < 4; ++dt) {
            Ob[(size_t)(q0 + 16 * w + g * 4 + 0) * 512 + 16 * dt + r] = f2bf(acc_o[dt][0] * il0);
            Ob[(size_t)(q0 + 16 * w + g * 4 + 1) * 512 + 16 * dt + r] = f2bf(acc_o[dt][1] * il1);
            Ob[(size_t)(q0 + 16 * w + g * 4 + 2) * 512 + 16 * dt + r] = f2bf(acc_o[dt][2] * il2);
            Ob[(size_t)(q0 + 16 * w + g * 4 + 3) * 512 + 16 * dt + r] = f2bf(acc_o[dt][3] * il3);
        }
        if (g == 0)
            Ml[((size_t)(s * 8 + b) * 8 + h) * q_rows + q0 + 16 * w + r] = make_float2(m_own, l_own);
    } else {
        unsigned short* O = Op + (size_t)b * o_bs + (size_t)h * 64;
        #pragma unroll
        for (int dt = 0; dt < 4; ++dt) {
            O[(size_t)(q0 + 16 * w + g * 4 + 0) * o_rs + 16 * dt + r] = f2bf(acc_o[dt][0] * il0);
            O[(size_t)(q0 + 16 * w + g * 4 + 1) * o_rs + 16 * dt + r] = f2bf(acc_o[dt][1] * il1);
            O[(size_t)(q0 + 16 * w + g * 4 + 2) * o_rs + 16 * dt + r] = f2bf(acc_o[dt][2] * il2);
            O[(size_t)(q0 + 16 * w + g * 4 + 3) * o_rs + 16 * dt + r] = f2bf(acc_o[dt][3] * il3);
        }
    }
}

// ---------------------------------------------------------------- combine NS KV-splits: O = sum_s w_s * Ohat_s
template<int NS, int QROWS>
__global__ __launch_bounds__(256) void combine_k(const unsigned short* __restrict__ opart,
                                                 long long part_stride,
                                                 const float2* __restrict__ Ml,
                                                 unsigned short* __restrict__ Oo)
{
    constexpr float C1 = 0.18033688011112042f;
    const int row = blockIdx.x;                 // 0..8*QROWS-1 (= b*QROWS + srow)
    const int b = row / QROWS, srow = row % QROWS;
    const int tid = threadIdx.x;
    const int h = tid >> 5, t = tid & 31;
    float2 ml[NS];
    float m = -INFINITY;
    #pragma unroll
    for (int s = 0; s < NS; ++s) {
        ml[s] = Ml[((size_t)(s * 8 + b) * 8 + h) * QROWS + srow];
        m = fmaxf(m, ml[s].x);
    }
    float wgt[NS];
    float wsum = 0.f;
    #pragma unroll
    for (int s = 0; s < NS; ++s) {
        wgt[s] = __builtin_amdgcn_exp2f((ml[s].x - m) * C1) * ml[s].y;
        wsum += wgt[s];
    }
    float inv = 1.f / wsum;
    const int col = h * 64 + t * 2;
    float acc0 = 0.f, acc1 = 0.f;
    #pragma unroll
    for (int s = 0; s < NS; ++s) {
        unsigned u = *(const unsigned*)&opart[(size_t)s * part_stride + (size_t)row * 512 + col];
        acc0 += wgt[s] * __builtin_bit_cast(float, (u & 0xffffu) << 16);
        acc1 += wgt[s] * __builtin_bit_cast(float, (u >> 16) << 16);
    }
    *(unsigned*)&Oo[(size_t)row * 512 + col] = cvt_pk_bf16(acc0 * inv, acc1 * inv);
}

// ---------------------------------------------------------------- layernorm D=512, fp32 in -> bf16 out
// 256 threads = 4 waves, each wave handles one row (grid = rows/4)
__global__ __launch_bounds__(256) void ln_k(const float* __restrict__ X, unsigned short* __restrict__ Y,
                                            const float* __restrict__ g, const float* __restrict__ bt)
{
    int row = blockIdx.x * 4 + (threadIdx.x >> 6);
    int lane = threadIdx.x & 63;
    const float* x = X + (size_t)row * 512;
    int c0 = lane * 4, c1 = 256 + lane * 4;
    float4 a0 = *(const float4*)&x[c0];
    float4 a1 = *(const float4*)&x[c1];
    float s  = a0.x + a0.y + a0.z + a0.w + a1.x + a1.y + a1.z + a1.w;
    float ss = a0.x * a0.x + a0.y * a0.y + a0.z * a0.z + a0.w * a0.w
             + a1.x * a1.x + a1.y * a1.y + a1.z * a1.z + a1.w * a1.w;
    #pragma unroll
    for (int off = 1; off < 64; off <<= 1) { s += __shfl_xor(s, off); ss += __shfl_xor(ss, off); }
    float mean = s * (1.f / 512.f);
    float var  = ss * (1.f / 512.f) - mean * mean;
    float rs = rsqrtf(var + 1e-5f);
    float4 g0 = *(const float4*)&g[c0], g1 = *(const float4*)&g[c1];
    float4 b0 = *(const float4*)&bt[c0], b1 = *(const float4*)&bt[c1];
    unsigned short* y = Y + (size_t)row * 512;
    ushort4 o0, o1;
    o0.x = f2bf((a0.x - mean) * rs * g0.x + b0.x);  o0.y = f2bf((a0.y - mean) * rs * g0.y + b0.y);
    o0.z = f2bf((a0.z - mean) * rs * g0.z + b0.z);  o0.w = f2bf((a0.w - mean) * rs * g0.w + b0.w);
    o1.x = f2bf((a1.x - mean) * rs * g1.x + b1.x);  o1.y = f2bf((a1.y - mean) * rs * g1.y + b1.y);
    o1.z = f2bf((a1.z - mean) * rs * g1.z + b1.z);  o1.w = f2bf((a1.w - mean) * rs * g1.w + b1.w);
    *(ushort4*)&y[c0] = o0;
    *(ushort4*)&y[c1] = o1;
}

// ---------------------------------------------------------------- gather gene embeddings -> bf16
__global__ __launch_bounds__(128) void gather_k(const float* __restrict__ ge, const int* __restrict__ ids,
                                                unsigned short* __restrict__ out)
{
    int gi = blockIdx.x, t = threadIdx.x;
    int id = ids[gi];
    float4 v = *(const float4*)&ge[(size_t)id * 512 + t * 4];
    ushort4 o;
    o.x = f2bf(v.x); o.y = f2bf(v.y); o.z = f2bf(v.z); o.w = f2bf(v.w);
    *(ushort4*)&out[(size_t)gi * 512 + t * 4] = o;
}

// ---------------------------------------------------------------- fused readout: pred = LN(z)*g+b . ro_w + ro_b
// 256 threads = 4 waves, each wave handles one row (grid = rows/4)
__global__ __launch_bounds__(256) void readout_k(const float* __restrict__ Z,
                                                 const float* __restrict__ g, const float* __restrict__ bt,
                                                 const float* __restrict__ rw, const float* __restrict__ rb,
                                                 float* __restrict__ pred)
{
    int row = blockIdx.x * 4 + (threadIdx.x >> 6);
    int lane = threadIdx.x & 63;
    const float* zr = Z + (size_t)row * 512;
    int c0 = lane * 4, c1 = 256 + lane * 4;
    float4 a0 = *(const float4*)&zr[c0];
    float4 a1 = *(const float4*)&zr[c1];
    float s  = a0.x + a0.y + a0.z + a0.w + a1.x + a1.y + a1.z + a1.w;
    float ss = a0.x * a0.x + a0.y * a0.y + a0.z * a0.z + a0.w * a0.w
             + a1.x * a1.x + a1.y * a1.y + a1.z * a1.z + a1.w * a1.w;
    #pragma unroll
    for (int off = 1; off < 64; off <<= 1) { s += __shfl_xor(s, off); ss += __shfl_xor(ss, off); }
    float mean = s * (1.f / 512.f);
    float var  = ss * (1.f / 512.f) - mean * mean;
    float rs = rsqrtf(var + 1e-5f);
    float4 g0 = *(const float4*)&g[c0], g1 = *(const float4*)&g[c1];
    float4 b0 = *(const float4*)&bt[c0], b1 = *(const float4*)&bt[c1];
    float4 w0 = *(const float4*)&rw[c0], w1 = *(const float4*)&rw[c1];
    float acc = 0.f;
    acc += ((a0.x - mean) * rs * g0.x + b0.x) * w0.x;
    acc += ((a0.y - mean) * rs * g0.y + b0.y) * w0.y;
    acc += ((a0.z - mean) * rs * g0.z + b0.z) * w0.z;
    acc += ((a0.w - mean) * rs * g0.w + b0.w) * w0.w;
    acc += ((a1.x - mean) * rs * g1.x + b1.x) * w1.x;
    acc += ((a1.y - mean) * rs * g1.y + b1.y) * w1.y;
    acc += ((a1.z - mean) * rs * g1.z + b1.z) * w1.z;
    acc += ((a1.w - mean) * rs * g1.w + b1.w) * w1.w;
    #pragma unroll
    for (int off = 1; off < 64; off <<= 1) acc += __shfl_xor(acc, off);
    if (lane == 0) pred[row] = acc + rb[0];
}

// ---------------------------------------------------------------- launch
extern "C" void kernel_launch(void* const* d_in, const int* in_sizes, int n_in,
                              void* d_out, int out_size, void* d_ws, size_t ws_size,
                              hipStream_t stream)
{
    (void)in_sizes; (void)n_in; (void)out_size; (void)ws_size;
    const float* windows    = (const float*)d_in[0];
    const int*   gene_ids   = (const int*)  d_in[1];
    const float* W_window   = (const float*)d_in[2];
    const float* enc_qkv_w  = (const float*)d_in[3];
    const float* enc_qkv_b  = (const float*)d_in[4];
    const float* enc_out_w  = (const float*)d_in[5];
    const float* enc_out_b  = (const float*)d_in[6];
    const float* enc_ln1_g  = (const float*)d_in[7];
    const float* enc_ln1_b  = (const float*)d_in[8];
    const float* enc_ln2_g  = (const float*)d_in[9];
    const float* enc_ln2_b  = (const float*)d_in[10];
    const float* enc_ff1_w  = (const float*)d_in[11];
    const float* enc_ff1_b  = (const float*)d_in[12];
    const float* enc_ff2_w  = (const float*)d_in[13];
    const float* enc_ff2_b  = (const float*)d_in[14];
    const float* gene_embed = (const float*)d_in[15];
    const float* ca_qkv_w   = (const float*)d_in[16];
    const float* ca_qkv_b   = (const float*)d_in[17];
    const float* ca_out_w   = (const float*)d_in[18];
    const float* ca_out_b   = (const float*)d_in[19];
    const float* ro_ln_g    = (const float*)d_in[20];
    const float* ro_ln_b    = (const float*)d_in[21];
    const float* ro_w       = (const float*)d_in[22];
    const float* ro_b       = (const float*)d_in[23];

    float* pred = (float*)d_out;
    float* z    = pred + (size_t)8 * 2048;

    // workspace carve-up (~79 MB)
    char* wsb = (char*)d_ws;
    char* wp = wsb;
    float* x = (float*)wp;                       wp += (size_t)4096 * 512 * 4;   // 8 MB   [0..8)
    unsigned short* x16   = (unsigned short*)wp; wp += (size_t)4096 * 512 * 2;   // 4 MB   [8..12)
    unsigned short* h16   = (unsigned short*)wp; wp += (size_t)4096 * 512 * 2;   // 4 MB   [12..16)
    unsigned short* qkv16 = (unsigned short*)wp; wp += (size_t)4096 * 1536 * 2;  // 12 MB  [16..28)
    unsigned short* ao16  = (unsigned short*)wp; wp += (size_t)4096 * 512 * 2;   // 4 MB   [28..32)
    unsigned short* big16 = (unsigned short*)wp; wp += (size_t)16384 * 512 * 2;  // 16 MB  [32..48)
    unsigned short* vt16  = (unsigned short*)wp; wp += (size_t)512 * 4096 * 2;   // 4 MB   [48..52)
    unsigned short* wall16 = (unsigned short*)wp;  // all bf16 weights, contiguous in cvt_all order:
    unsigned short* wW16     = wall16;
    unsigned short* wqkv16   = wW16     + (size_t)512 * 1024;
    unsigned short* wout16   = wqkv16   + (size_t)4 * 1536 * 512;
    unsigned short* wff116   = wout16   + (size_t)4 * 512 * 512;
    unsigned short* wff216   = wff116   + (size_t)4 * 2048 * 512;
    unsigned short* wcaqkv16 = wff216   + (size_t)4 * 512 * 2048;
    unsigned short* wcaout16 = wcaqkv16 + (size_t)1536 * 512;
    // aliases (lifetimes disjoint)
    unsigned short* pw16    = big16;                         // 4096x1024 (stage 1)
    unsigned short* ff116   = big16;                         // 4096x2048 (FF, per layer)
    unsigned short* oc16    = big16;                         // 16384x512 (cross output)
    unsigned short* opart16 = big16;                         // self: 4x(4096x512) partials in big16
    float2* mlbuf = (float2*)(qkv16 + (size_t)4096 * 1024);  // qkv16 tail [24..28) MB
    unsigned short* ge16  = qkv16;                           // 2048x512   [16..18) MB
    unsigned short* qg16  = qkv16 + (size_t)2048 * 512;      // 2048x512   [18..20) MB
    unsigned short* kc16  = qkv16 + (size_t)2 * 2048 * 512;  // 4096x512   [20..24) MB

    // weights fp32 -> bf16, single launch
    cvt_all_k<<<13824, 256, 0, stream>>>(W_window, enc_qkv_w, enc_out_w, enc_ff1_w,
                                         enc_ff2_w, ca_qkv_w, ca_out_w, wall16);

    // 1) pool + window projection + posenc -> x (fp32)
    pool_windows_k<<<4096, 256, 0, stream>>>(windows, pw16);
    gemm_bf16_k<64, 64, false, false, false, false, true, true, false><<<dim3(64, 8), 256, 0, stream>>>(
        pw16, wW16, nullptr, nullptr, x, nullptr, 4096, 512, 1024);

    // 2) encoder layers
    for (int l = 0; l < 4; ++l) {
        const unsigned short* wl = wqkv16 + (size_t)l * 1536 * 512;
        ln_k<<<1024, 256, 0, stream>>>(x, h16, enc_ln1_g + l * 512, enc_ln1_b + l * 512);
        // QK projection (cols 0..1023 of qkv)
        gemm_bf16_k<64, 64, true, false, false, false, false, false, true><<<dim3(64, 16), 256, 0, stream>>>(
            h16, wl, enc_qkv_b + l * 1536, nullptr, nullptr, qkv16, 4096, 1024, 512);
        // V^T = Wv * h^T  (bias per row)
        gemm_bf16_k<64, 64, true, true, false, false, false, false, true><<<dim3(8, 64), 256, 0, stream>>>(
            wl + (size_t)1024 * 512, h16, enc_qkv_b + l * 1536 + 1024, nullptr,
            nullptr, vt16, 512, 4096, 512);
        // flash, KV-split x4 (nc=2 -> one pair-iteration), XCD-colocated grid
        flashc_k<true><<<dim3(64, 8, 4), 256, 0, stream>>>(
            qkv16, (long long)512 * 1024, 1024,
            qkv16 + 512, (long long)512 * 1024, 1024,
            vt16, (long long)64 * 4096, 512LL, 4096,
            nullptr, 0LL, 0,
            opart16, (long long)4096 * 512, 512, mlbuf, 2);
        combine_k<4, 512><<<4096, 256, 0, stream>>>(opart16, (long long)4096 * 512, mlbuf, ao16);
        gemm_bf16_k<64, 64, true, false, true, false, false, true, false><<<dim3(64, 8), 256, 0, stream>>>(
            ao16, wout16 + (size_t)l * 512 * 512, enc_out_b + l * 512, x, x, nullptr, 4096, 512, 512);
        ln_k<<<1024, 256, 0, stream>>>(x, h16, enc_ln2_g + l * 512, enc_ln2_b + l * 512);
        gemm_bf16_k<64, 64, true, false, false, true, false, false, true><<<dim3(64, 32), 256, 0, stream>>>(
            h16, wff116 + (size_t)l * 2048 * 512, enc_ff1_b + l * 2048, nullptr,
            nullptr, ff116, 4096, 2048, 512);
        if (l == 3)
            gemm_bf16_k<64, 64, true, false, true, false, false, true, true><<<dim3(64, 8), 256, 0, stream>>>(
                ff116, wff216 + (size_t)l * 512 * 2048, enc_ff2_b + l * 512, x, x, x16, 4096, 512, 2048);
        else
            gemm_bf16_k<64, 64, true, false, true, false, false, true, false><<<dim3(64, 8), 256, 0, stream>>>(
                ff116, wff216 + (size_t)l * 512 * 2048, enc_ff2_b + l * 512, x, x, nullptr, 4096, 512, 2048);
    }

    // 3) cross-attention (flash unsplit, nc=8 -> 4 pair-iterations, XCD-colocated grid)
    gather_k<<<2048, 128, 0, stream>>>(gene_embed, gene_ids, ge16);
    gemm_bf16_k<64, 64, true, false, false, false, false, false, true><<<dim3(32, 8), 256, 0, stream>>>(
        ge16, wcaqkv16, ca_qkv_b, nullptr, nullptr, qg16, 2048, 512, 512);
    gemm_bf16_k<64, 64, true, false, false, false, false, false, true><<<dim3(64, 8), 256, 0, stream>>>(
        x16, wcaqkv16 + (size_t)512 * 512, ca_qkv_b + 512, nullptr, nullptr, kc16, 4096, 512, 512);
    gemm_bf16_k<64, 64, true, true, false, false, false, false, true><<<dim3(8, 64), 256, 0, stream>>>(
        wcaqkv16 + (size_t)1024 * 512, x16, ca_qkv_b + 1024, nullptr, nullptr, vt16, 512, 4096, 512);
    flashc_k<false><<<dim3(64, 32, 1), 256, 0, stream>>>(
        qg16, 0LL, 512,
        kc16, (long long)512 * 512, 512,
        vt16, (long long)64 * 4096, 512LL, 4096,
        oc16, (long long)2048 * 512, 512,
        nullptr, 0LL, 0, nullptr, 8);
    gemm_bf16_k<64, 64, true, false, false, false, false, true, false><<<dim3(256, 8), 256, 0, stream>>>(
        oc16, wcaout16, ca_out_b, nullptr, z, nullptr, 16384, 512, 512);

    // 4) readout
    readout_k<<<4096, 256, 0, stream>>>(z, ro_ln_g, ro_ln_b, ro_w, ro_b, pred);
}

// Round 19
// 493.381 us; speedup vs baseline: 1.0392x; 1.0392x over previous
//
#include <hip/hip_runtime.h>
#include <math.h>

// MultiomicTransformer on MI355X — Round 19: fuse independent GEMMs into single launches
// (encoder: QK-proj + V^T; cross: qg + kc + vt). Flash = R16/R17 proven version.
// B=8 W=2048 WIN=1024 D=512 NH=8 HD=64 DFF=2048 L=4 KS=4 G=2048 S=512

typedef __attribute__((ext_vector_type(8))) short short8v;
typedef __attribute__((ext_vector_type(4))) float float4v;
typedef const __attribute__((address_space(1))) void* gas_t;
typedef __attribute__((address_space(3))) void* las_t;

__device__ inline unsigned short f2bf(float f) {
    unsigned int u = __builtin_bit_cast(unsigned int, f);
    return (unsigned short)((u + 0x7fffu + ((u >> 16) & 1u)) >> 16);   // RNE
}

__device__ inline unsigned cvt_pk_bf16(float lo, float hi) {          // [bf16(lo) | bf16(hi)<<16]
    unsigned r;
    asm("v_cvt_pk_bf16_f32 %0, %1, %2" : "=v"(r) : "v"(lo), "v"(hi));
    return r;
}

// ---------------------------------------------------------------- all-weights fp32 -> bf16 (single launch)
__global__ __launch_bounds__(256) void cvt_all_k(
    const float* __restrict__ s0, const float* __restrict__ s1, const float* __restrict__ s2,
    const float* __restrict__ s3, const float* __restrict__ s4, const float* __restrict__ s5,
    const float* __restrict__ s6, unsigned short* __restrict__ dst)
{
    constexpr int c1 = 131072, c2 = 917504, c3 = 1179648, c4 = 2228224, c5 = 3276800, c6 = 3473408;
    int i = blockIdx.x * 256 + threadIdx.x;            // grid exactly covers 3538944 float4s
    const float* s = s0; int base = 0;
    if (i >= c1) { s = s1; base = c1; }
    if (i >= c2) { s = s2; base = c2; }
    if (i >= c3) { s = s3; base = c3; }
    if (i >= c4) { s = s4; base = c4; }
    if (i >= c5) { s = s5; base = c5; }
    if (i >= c6) { s = s6; base = c6; }
    float4 v = ((const float4*)s)[i - base];
    ushort4 o;
    o.x = f2bf(v.x); o.y = f2bf(v.y); o.z = f2bf(v.z); o.w = f2bf(v.w);
    ((ushort4*)dst)[i] = o;
}

// ---------------------------------------------------------------- pool mean-4 (commutes with win-proj), bf16 out
__global__ __launch_bounds__(256) void pool_windows_k(const float* __restrict__ win,
                                                      unsigned short* __restrict__ pw)
{
    int idx = blockIdx.x * 256 + threadIdx.x;
    int n = idx >> 8, c4 = (idx & 255) << 2;
    const float* base = win + (size_t)n * 4096 + c4;
    float4 a = *(const float4*)(base);
    float4 b2 = *(const float4*)(base + 1024);
    float4 c = *(const float4*)(base + 2048);
    float4 d = *(const float4*)(base + 3072);
    ushort4 r;
    r.x = f2bf((a.x + b2.x + c.x + d.x) * 0.25f);
    r.y = f2bf((a.y + b2.y + c.y + d.y) * 0.25f);
    r.z = f2bf((a.z + b2.z + c.z + d.z) * 0.25f);
    r.w = f2bf((a.w + b2.w + c.w + d.w) * 0.25f);
    ((ushort4*)pw)[idx] = r;
}

// ---------------------------------------------------------------- GEMM body (64x64 tile, BK=64, dbuf, counted vmcnt)
// C[M,N] = A[M,K] * Bw[N,K]^T. LDS passed in (2x4096 elems each) so fused
// dispatchers share one allocation across branch instantiations.
template<bool BIAS, bool BROW, bool RES, bool RELU, bool POSENC, bool O32, bool O16>
__device__ __forceinline__ void gemm_body(
    unsigned short* AsL, unsigned short* BsL,
    const unsigned short* __restrict__ A, const unsigned short* __restrict__ Bw,
    const float* __restrict__ bias, const float* __restrict__ Res,
    float* __restrict__ C32, unsigned short* __restrict__ C16,
    int M, int N, int K, int bx, int by)
{
    constexpr int BK = 64, CPR = 8;
    const int tid = threadIdx.x;
    const int lane = tid & 63;
    const int m0 = bx * 64, n0 = by * 64;
    const int wid = tid >> 6;
    const int wr = wid >> 1, wc = wid & 1;
    const int r = lane & 15, g = lane >> 4;

    const unsigned short* gA[2];
    const unsigned short* gB[2];
    #pragma unroll
    for (int j = 0; j < 2; ++j) {
        int c = tid + j * 256, row = c / CPR, cc = c % CPR;
        gA[j] = A + (size_t)(m0 + row) * K + ((cc ^ (row & 7)) * 8);
        gB[j] = Bw + (size_t)(n0 + row) * K + ((cc ^ (row & 7)) * 8);
    }

    auto stage = [&](int bi, int k0) {
        #pragma unroll
        for (int j = 0; j < 2; ++j) {
            __builtin_amdgcn_global_load_lds((gas_t)(gA[j] + k0),
                (las_t)(AsL + bi * 4096 + (tid + j * 256) * 8), 16, 0, 0);
            __builtin_amdgcn_global_load_lds((gas_t)(gB[j] + k0),
                (las_t)(BsL + bi * 4096 + (tid + j * 256) * 8), 16, 0, 0);
        }
    };

    float4v acc[2][2];
    float4v z4 = {0.f, 0.f, 0.f, 0.f};
    #pragma unroll
    for (int i = 0; i < 2; ++i)
        #pragma unroll
        for (int j = 0; j < 2; ++j) acc[i][j] = z4;

    stage(0, 0);
    int buf = 0;
    for (int k0 = 0; k0 < K; k0 += BK) {
        if (k0 + BK < K) {
            stage(buf ^ 1, k0 + BK);                      // prefetch: stays in flight across barrier
            asm volatile("s_waitcnt vmcnt(4)" ::: "memory");
        } else {
            asm volatile("s_waitcnt vmcnt(0)" ::: "memory");
        }
        __builtin_amdgcn_sched_barrier(0);
        __builtin_amdgcn_s_barrier();                     // raw: no compiler drain
        __builtin_amdgcn_sched_barrier(0);
        #pragma unroll
        for (int kk = 0; kk < 2; ++kk) {
            const int cx = ((kk * 4 + g) ^ (r & 7)) * 8;
            short8v a[2], b[2];
            #pragma unroll
            for (int mi = 0; mi < 2; ++mi)
                a[mi] = *(const short8v*)&AsL[buf * 4096 + (32 * wr + 16 * mi + r) * BK + cx];
            #pragma unroll
            for (int ni = 0; ni < 2; ++ni)
                b[ni] = *(const short8v*)&BsL[buf * 4096 + (32 * wc + 16 * ni + r) * BK + cx];
            #pragma unroll
            for (int mi = 0; mi < 2; ++mi)
                #pragma unroll
                for (int ni = 0; ni < 2; ++ni)
                    acc[mi][ni] = __builtin_amdgcn_mfma_f32_16x16x32_bf16(a[mi], b[ni], acc[mi][ni], 0, 0, 0);
        }
        __builtin_amdgcn_sched_barrier(0);
        __builtin_amdgcn_s_barrier();                     // skew bound: reads of buf done before reuse
        buf ^= 1;
    }

    #pragma unroll
    for (int mi = 0; mi < 2; ++mi) {
        #pragma unroll
        for (int ni = 0; ni < 2; ++ni) {
            const int row0 = m0 + 32 * wr + 16 * mi + g * 4;
            const int col  = n0 + 32 * wc + 16 * ni + r;
            float bv = (BIAS && !BROW) ? bias[col] : 0.f;
            float fr = 0.f;
            if (POSENC) fr = __expf((float)(col & ~1) * -0.01798894600f);
            #pragma unroll
            for (int q = 0; q < 4; ++q) {
                const int row = row0 + q;
                float v = acc[mi][ni][q] + bv;
                if (BIAS && BROW) v += bias[row];
                if (POSENC) {
                    float ang = (float)(row & 511) * fr;
                    v += (col & 1) ? __cosf(ang) : __sinf(ang);
                }
                if (RES) v += Res[(size_t)row * N + col];
                if (RELU) v = fmaxf(v, 0.0f);
                if (O32) C32[(size_t)row * N + col] = v;
                if (O16) C16[(size_t)row * N + col] = f2bf(v);
            }
        }
    }
}

// ---------------------------------------------------------------- standalone GEMM wrapper
template<bool BIAS, bool BROW, bool RES, bool RELU, bool POSENC, bool O32, bool O16>
__global__ __launch_bounds__(256) void gemm_bf16_k(
    const unsigned short* __restrict__ A, const unsigned short* __restrict__ Bw,
    const float* __restrict__ bias, const float* __restrict__ Res,
    float* __restrict__ C32, unsigned short* __restrict__ C16,
    int M, int N, int K)
{
    __shared__ __align__(16) unsigned short As[2 * 4096];
    __shared__ __align__(16) unsigned short Bs[2 * 4096];
    gemm_body<BIAS, BROW, RES, RELU, POSENC, O32, O16>(
        As, Bs, A, Bw, bias, Res, C32, C16, M, N, K, blockIdx.x, blockIdx.y);
}

// ---------------------------------------------------------------- fused encoder QKV: QK-proj (1024 blk) + V^T (512 blk)
__global__ __launch_bounds__(256) void gemm_qkv_fused_k(
    const unsigned short* __restrict__ h16,
    const unsigned short* __restrict__ wqk, const float* __restrict__ bqk,
    const unsigned short* __restrict__ wv,  const float* __restrict__ bv,
    unsigned short* __restrict__ qkv16, unsigned short* __restrict__ vt16)
{
    __shared__ __align__(16) unsigned short As[2 * 4096];
    __shared__ __align__(16) unsigned short Bs[2 * 4096];
    const int bid = blockIdx.x;
    if (bid < 1024) {
        // QK projection: C[4096,1024] = h16 * wqk^T  (grid was 64 x 16, x fastest)
        gemm_body<true, false, false, false, false, false, true>(
            As, Bs, h16, wqk, bqk, nullptr, nullptr, qkv16, 4096, 1024, 512,
            bid & 63, bid >> 6);
    } else {
        // V^T: C[512,4096] = wv * h16^T, bias per row  (grid was 8 x 64)
        const int b2 = bid - 1024;
        gemm_body<true, true, false, false, false, false, true>(
            As, Bs, wv, h16, bv, nullptr, nullptr, vt16, 512, 4096, 512,
            b2 & 7, b2 >> 3);
    }
}

// ---------------------------------------------------------------- fused cross projections: qg (256) + kc (512) + vt (512)
__global__ __launch_bounds__(256) void gemm_cross_fused_k(
    const unsigned short* __restrict__ ge16, const unsigned short* __restrict__ x16,
    const unsigned short* __restrict__ wcaqkv, const float* __restrict__ cab,
    unsigned short* __restrict__ qg16, unsigned short* __restrict__ kc16,
    unsigned short* __restrict__ vt16)
{
    __shared__ __align__(16) unsigned short As[2 * 4096];
    __shared__ __align__(16) unsigned short Bs[2 * 4096];
    const int bid = blockIdx.x;
    if (bid < 256) {
        // qg: C[2048,512] = ge16 * Wq^T  (grid was 32 x 8)
        gemm_body<true, false, false, false, false, false, true>(
            As, Bs, ge16, wcaqkv, cab, nullptr, nullptr, qg16, 2048, 512, 512,
            bid & 31, bid >> 5);
    } else if (bid < 768) {
        // kc: C[4096,512] = x16 * Wk^T  (grid was 64 x 8)
        const int b2 = bid - 256;
        gemm_body<true, false, false, false, false, false, true>(
            As, Bs, x16, wcaqkv + (size_t)512 * 512, cab + 512, nullptr, nullptr,
            kc16, 4096, 512, 512, b2 & 63, b2 >> 6);
    } else {
        // vt: C[512,4096] = Wv * x16^T, bias per row  (grid was 8 x 64)
        const int b3 = bid - 768;
        gemm_body<true, true, false, false, false, false, true>(
            As, Bs, wcaqkv + (size_t)1024 * 512, x16, cab + 1024, nullptr, nullptr,
            vt16, 512, 4096, 512, b3 & 7, b3 >> 3);
    }
}

// ---------------------------------------------------------------- flash attention (R16/R17: single-buffered, XCD grid)
template<bool SPLIT>
__global__ __launch_bounds__(256) void flashc_k(
    const unsigned short* __restrict__ Qp, long long q_bs, int q_rs,
    const unsigned short* __restrict__ Kp, long long k_bs, int k_rs,
    const unsigned short* __restrict__ Vtp, long long v_hs, long long v_bs, int v_rs,
    unsigned short* __restrict__ Op, long long o_bs, int o_rs,
    unsigned short* __restrict__ opart, long long part_stride, int q_rows,
    float2* __restrict__ Ml, int nc)
{
    constexpr float C1 = 0.18033688011112042f;   // 0.125 * log2(e)
    __shared__ __align__(16) unsigned short Kb[64 * 64];
    __shared__ __align__(16) unsigned short Vb[64 * 64];
    __shared__ __align__(16) unsigned short Ps[64 * 64];
    const int hb = blockIdx.x, qt = blockIdx.y, s = blockIdx.z;
    const int h = hb & 7, b = hb >> 3;
    const unsigned short* Q  = Qp  + (size_t)b * q_bs + (size_t)h * 64;
    const unsigned short* Kg = Kp  + (size_t)b * k_bs + (size_t)h * 64 + (size_t)(s * nc * 64) * k_rs;
    const unsigned short* Vg = Vtp + (size_t)h * v_hs + (size_t)b * v_bs + (size_t)(s * nc) * 64;
    const int q0 = qt * 64;
    const int tid = threadIdx.x, lane = tid & 63, w = tid >> 6;
    const int r = lane & 15, g = lane >> 4;
    const int sw8 = (r & 7) * 8;
    const int cA = (g * 8) ^ sw8;
    const int cB = ((g + 4) * 8) ^ sw8;
    const int prow = (16 * w + r) * 64;

    const unsigned short* qrow = Q + (size_t)(q0 + 16 * w + r) * q_rs + g * 8;
    short8v qf0 = *(const short8v*)(qrow);
    short8v qf1 = *(const short8v*)(qrow + 32);

    const int r0 = tid >> 3, cc = tid & 7;
    const int srcc = (cc ^ (r0 & 7)) * 8;
    auto stage = [&](int c) {
        const unsigned short* kc_ = Kg + (size_t)c * 64 * k_rs;
        const unsigned short* vc_ = Vg + (size_t)c * 64;
        __builtin_amdgcn_global_load_lds((gas_t)(kc_ + (size_t)r0 * k_rs + srcc),
                                         (las_t)(&Kb[tid * 8]), 16, 0, 0);
        __builtin_amdgcn_global_load_lds((gas_t)(kc_ + (size_t)(r0 + 32) * k_rs + srcc),
                                         (las_t)(&Kb[(tid + 256) * 8]), 16, 0, 0);
        __builtin_amdgcn_global_load_lds((gas_t)(vc_ + (size_t)r0 * v_rs + srcc),
                                         (las_t)(&Vb[tid * 8]), 16, 0, 0);
        __builtin_amdgcn_global_load_lds((gas_t)(vc_ + (size_t)(r0 + 32) * v_rs + srcc),
                                         (las_t)(&Vb[(tid + 256) * 8]), 16, 0, 0);
    };

    float4v acc_o[4];
    float4v z4 = {0.f, 0.f, 0.f, 0.f};
    #pragma unroll
    for (int dt = 0; dt < 4; ++dt) acc_o[dt] = z4;
    float m_own = -INFINITY, l_own = 0.f;

    for (int c = 0; c < nc; ++c) {
        stage(c);
        __syncthreads();                       // drains loads; K/V visible to all waves

        __builtin_amdgcn_s_setprio(1);
        float4v accs[4];
        #pragma unroll
        for (int t = 0; t < 4; ++t) {
            accs[t] = z4;
            const unsigned short* krow = Kb + (16 * t + r) * 64;
            short8v kf0 = *(const short8v*)(krow + cA);
            short8v kf1 = *(const short8v*)(krow + cB);
            accs[t] = __builtin_amdgcn_mfma_f32_16x16x32_bf16(kf0, qf0, accs[t], 0, 0, 0);
            accs[t] = __builtin_amdgcn_mfma_f32_16x16x32_bf16(kf1, qf1, accs[t], 0, 0, 0);
        }
        __builtin_amdgcn_s_setprio(0);

        float m0_ = fmaxf(fmaxf(accs[0][0], accs[0][1]), fmaxf(accs[0][2], accs[0][3]));
        float m1_ = fmaxf(fmaxf(accs[1][0], accs[1][1]), fmaxf(accs[1][2], accs[1][3]));
        float m2_ = fmaxf(fmaxf(accs[2][0], accs[2][1]), fmaxf(accs[2][2], accs[2][3]));
        float m3_ = fmaxf(fmaxf(accs[3][0], accs[3][1]), fmaxf(accs[3][2], accs[3][3]));
        float sm = fmaxf(fmaxf(m0_, m1_), fmaxf(m2_, m3_));
        sm = fmaxf(sm, __shfl_xor(sm, 16));
        sm = fmaxf(sm, __shfl_xor(sm, 32));

        if (__any(sm > m_own + 64.f)) {
            float mn = fmaxf(m_own, sm);
            float alpha = __builtin_amdgcn_exp2f((m_own - mn) * C1);   // first chunk: 0
            m_own = mn;
            float a0_ = __shfl(alpha, g * 4 + 0);
            float a1_ = __shfl(alpha, g * 4 + 1);
            float a2_ = __shfl(alpha, g * 4 + 2);
            float a3_ = __shfl(alpha, g * 4 + 3);
            #pragma unroll
            for (int dt = 0; dt < 4; ++dt) {
                acc_o[dt][0] *= a0_; acc_o[dt][1] *= a1_;
                acc_o[dt][2] *= a2_; acc_o[dt][3] *= a3_;
            }
            l_own *= alpha;
        }

        const float m2c = m_own * C1;
        float p[4][4];
        float rsum = 0.f;
        #pragma unroll
        for (int t = 0; t < 4; ++t)
            #pragma unroll
            for (int j = 0; j < 4; ++j) {
                float pv = __builtin_amdgcn_exp2f(__builtin_fmaf(accs[t][j], C1, -m2c));
                p[t][j] = pv; rsum += pv;
            }
        rsum += __shfl_xor(rsum, 16);
        rsum += __shfl_xor(rsum, 32);
        l_own += rsum;

        #pragma unroll
        for (int t = 0; t < 4; ++t) {
            uint2 uu;
            uu.x = cvt_pk_bf16(p[t][0], p[t][1]);
            uu.y = cvt_pk_bf16(p[t][2], p[t][3]);
            int pc = (((2 * t + (g >> 1)) * 8) ^ sw8) + (g & 1) * 4;
            *(uint2*)&Ps[prow + pc] = uu;
        }

        __builtin_amdgcn_s_setprio(1);
        short8v pf0 = *(const short8v*)&Ps[prow + cA];
        short8v pf1 = *(const short8v*)&Ps[prow + cB];
        #pragma unroll
        for (int dt = 0; dt < 4; ++dt) {
            const unsigned short* vrow = Vb + (16 * dt + r) * 64;
            short8v vf0 = *(const short8v*)(vrow + cA);
            short8v vf1 = *(const short8v*)(vrow + cB);
            acc_o[dt] = __builtin_amdgcn_mfma_f32_16x16x32_bf16(pf0, vf0, acc_o[dt], 0, 0, 0);
            acc_o[dt] = __builtin_amdgcn_mfma_f32_16x16x32_bf16(pf1, vf1, acc_o[dt], 0, 0, 0);
        }
        __builtin_amdgcn_s_setprio(0);

        __syncthreads();                       // all waves done reading K/V before next chunk's stage
    }

    float il0 = 1.f / __shfl(l_own, g * 4 + 0);
    float il1 = 1.f / __shfl(l_own, g * 4 + 1);
    float il2 = 1.f / __shfl(l_own, g * 4 + 2);
    float il3 = 1.f / __shfl(l_own, g * 4 + 3);
    if (SPLIT) {
        unsigned short* Ob = opart + (size_t)s * part_stride
                           + ((size_t)(b * q_rows)) * 512 + h * 64;
        #pragma unroll
        for (int dt = 0; dt < 4; ++dt) {
            Ob[(size_t)(q0 + 16 * w + g * 4 + 0) * 512 + 16 * dt + r] = f2bf(acc_o[dt][0] * il0);
            Ob[(size_t)(q0 + 16 * w + g * 4 + 1) * 512 + 16 * dt + r] = f2bf(acc_o[dt][1] * il1);
            Ob[(size_t)(q0 + 16 * w + g * 4 + 2) * 512 + 16 * dt + r] = f2bf(acc_o[dt][2] * il2);
            Ob[(size_t)(q0 + 16 * w + g * 4 + 3) * 512 + 16 * dt + r] = f2bf(acc_o[dt][3] * il3);
        }
        if (g == 0)
            Ml[((size_t)(s * 8 + b) * 8 + h) * q_rows + q0 + 16 * w + r] = make_float2(m_own, l_own);
    } else {
        unsigned short* O = Op + (size_t)b * o_bs + (size_t)h * 64;
        #pragma unroll
        for (int dt = 0; dt < 4; ++dt) {
            O[(size_t)(q0 + 16 * w + g * 4 + 0) * o_rs + 16 * dt + r] = f2bf(acc_o[dt][0] * il0);
            O[(size_t)(q0 + 16 * w + g * 4 + 1) * o_rs + 16 * dt + r] = f2bf(acc_o[dt][1] * il1);
            O[(size_t)(q0 + 16 * w + g * 4 + 2) * o_rs + 16 * dt + r] = f2bf(acc_o[dt][2] * il2);
            O[(size_t)(q0 + 16 * w + g * 4 + 3) * o_rs + 16 * dt + r] = f2bf(acc_o[dt][3] * il3);
        }
    }
}

// ---------------------------------------------------------------- combine NS KV-splits: O = sum_s w_s * Ohat_s
template<int NS, int QROWS>
__global__ __launch_bounds__(256) void combine_k(const unsigned short* __restrict__ opart,
                                                 long long part_stride,
                                                 const float2* __restrict__ Ml,
                                                 unsigned short* __restrict__ Oo)
{
    constexpr float C1 = 0.18033688011112042f;
    const int row = blockIdx.x;                 // 0..8*QROWS-1 (= b*QROWS + srow)
    const int b = row / QROWS, srow = row % QROWS;
    const int tid = threadIdx.x;
    const int h = tid >> 5, t = tid & 31;
    float2 ml[NS];
    float m = -INFINITY;
    #pragma unroll
    for (int s = 0; s < NS; ++s) {
        ml[s] = Ml[((size_t)(s * 8 + b) * 8 + h) * QROWS + srow];
        m = fmaxf(m, ml[s].x);
    }
    float wgt[NS];
    float wsum = 0.f;
    #pragma unroll
    for (int s = 0; s < NS; ++s) {
        wgt[s] = __builtin_amdgcn_exp2f((ml[s].x - m) * C1) * ml[s].y;
        wsum += wgt[s];
    }
    float inv = 1.f / wsum;
    const int col = h * 64 + t * 2;
    float acc0 = 0.f, acc1 = 0.f;
    #pragma unroll
    for (int s = 0; s < NS; ++s) {
        unsigned u = *(const unsigned*)&opart[(size_t)s * part_stride + (size_t)row * 512 + col];
        acc0 += wgt[s] * __builtin_bit_cast(float, (u & 0xffffu) << 16);
        acc1 += wgt[s] * __builtin_bit_cast(float, (u >> 16) << 16);
    }
    *(unsigned*)&Oo[(size_t)row * 512 + col] = cvt_pk_bf16(acc0 * inv, acc1 * inv);
}

// ---------------------------------------------------------------- layernorm D=512, fp32 in -> bf16 out (4 rows/block)
__global__ __launch_bounds__(256) void ln_k(const float* __restrict__ X, unsigned short* __restrict__ Y,
                                            const float* __restrict__ g, const float* __restrict__ bt)
{
    int row = blockIdx.x * 4 + (threadIdx.x >> 6);
    int lane = threadIdx.x & 63;
    const float* x = X + (size_t)row * 512;
    int c0 = lane * 4, c1 = 256 + lane * 4;
    float4 a0 = *(const float4*)&x[c0];
    float4 a1 = *(const float4*)&x[c1];
    float s  = a0.x + a0.y + a0.z + a0.w + a1.x + a1.y + a1.z + a1.w;
    float ss = a0.x * a0.x + a0.y * a0.y + a0.z * a0.z + a0.w * a0.w
             + a1.x * a1.x + a1.y * a1.y + a1.z * a1.z + a1.w * a1.w;
    #pragma unroll
    for (int off = 1; off < 64; off <<= 1) { s += __shfl_xor(s, off); ss += __shfl_xor(ss, off); }
    float mean = s * (1.f / 512.f);
    float var  = ss * (1.f / 512.f) - mean * mean;
    float rs = rsqrtf(var + 1e-5f);
    float4 g0 = *(const float4*)&g[c0], g1 = *(const float4*)&g[c1];
    float4 b0 = *(const float4*)&bt[c0], b1 = *(const float4*)&bt[c1];
    unsigned short* y = Y + (size_t)row * 512;
    ushort4 o0, o1;
    o0.x = f2bf((a0.x - mean) * rs * g0.x + b0.x);  o0.y = f2bf((a0.y - mean) * rs * g0.y + b0.y);
    o0.z = f2bf((a0.z - mean) * rs * g0.z + b0.z);  o0.w = f2bf((a0.w - mean) * rs * g0.w + b0.w);
    o1.x = f2bf((a1.x - mean) * rs * g1.x + b1.x);  o1.y = f2bf((a1.y - mean) * rs * g1.y + b1.y);
    o1.z = f2bf((a1.z - mean) * rs * g1.z + b1.z);  o1.w = f2bf((a1.w - mean) * rs * g1.w + b1.w);
    *(ushort4*)&y[c0] = o0;
    *(ushort4*)&y[c1] = o1;
}

// ---------------------------------------------------------------- gather gene embeddings -> bf16
__global__ __launch_bounds__(128) void gather_k(const float* __restrict__ ge, const int* __restrict__ ids,
                                                unsigned short* __restrict__ out)
{
    int gi = blockIdx.x, t = threadIdx.x;
    int id = ids[gi];
    float4 v = *(const float4*)&ge[(size_t)id * 512 + t * 4];
    ushort4 o;
    o.x = f2bf(v.x); o.y = f2bf(v.y); o.z = f2bf(v.z); o.w = f2bf(v.w);
    *(ushort4*)&out[(size_t)gi * 512 + t * 4] = o;
}

// ---------------------------------------------------------------- fused readout (4 rows/block)
__global__ __launch_bounds__(256) void readout_k(const float* __restrict__ Z,
                                                 const float* __restrict__ g, const float* __restrict__ bt,
                                                 const float* __restrict__ rw, const float* __restrict__ rb,
                                                 float* __restrict__ pred)
{
    int row = blockIdx.x * 4 + (threadIdx.x >> 6);
    int lane = threadIdx.x & 63;
    const float* zr = Z + (size_t)row * 512;
    int c0 = lane * 4, c1 = 256 + lane * 4;
    float4 a0 = *(const float4*)&zr[c0];
    float4 a1 = *(const float4*)&zr[c1];
    float s  = a0.x + a0.y + a0.z + a0.w + a1.x + a1.y + a1.z + a1.w;
    float ss = a0.x * a0.x + a0.y * a0.y + a0.z * a0.z + a0.w * a0.w
             + a1.x * a1.x + a1.y * a1.y + a1.z * a1.z + a1.w * a1.w;
    #pragma unroll
    for (int off = 1; off < 64; off <<= 1) { s += __shfl_xor(s, off); ss += __shfl_xor(ss, off); }
    float mean = s * (1.f / 512.f);
    float var  = ss * (1.f / 512.f) - mean * mean;
    float rs = rsqrtf(var + 1e-5f);
    float4 g0 = *(const float4*)&g[c0], g1 = *(const float4*)&g[c1];
    float4 b0 = *(const float4*)&bt[c0], b1 = *(const float4*)&bt[c1];
    float4 w0 = *(const float4*)&rw[c0], w1 = *(const float4*)&rw[c1];
    float acc = 0.f;
    acc += ((a0.x - mean) * rs * g0.x + b0.x) * w0.x;
    acc += ((a0.y - mean) * rs * g0.y + b0.y) * w0.y;
    acc += ((a0.z - mean) * rs * g0.z + b0.z) * w0.z;
    acc += ((a0.w - mean) * rs * g0.w + b0.w) * w0.w;
    acc += ((a1.x - mean) * rs * g1.x + b1.x) * w1.x;
    acc += ((a1.y - mean) * rs * g1.y + b1.y) * w1.y;
    acc += ((a1.z - mean) * rs * g1.z + b1.z) * w1.z;
    acc += ((a1.w - mean) * rs * g1.w + b1.w) * w1.w;
    #pragma unroll
    for (int off = 1; off < 64; off <<= 1) acc += __shfl_xor(acc, off);
    if (lane == 0) pred[row] = acc + rb[0];
}

// ---------------------------------------------------------------- launch
extern "C" void kernel_launch(void* const* d_in, const int* in_sizes, int n_in,
                              void* d_out, int out_size, void* d_ws, size_t ws_size,
                              hipStream_t stream)
{
    (void)in_sizes; (void)n_in; (void)out_size; (void)ws_size;
    const float* windows    = (const float*)d_in[0];
    const int*   gene_ids   = (const int*)  d_in[1];
    const float* W_window   = (const float*)d_in[2];
    const float* enc_qkv_w  = (const float*)d_in[3];
    const float* enc_qkv_b  = (const float*)d_in[4];
    const float* enc_out_w  = (const float*)d_in[5];
    const float* enc_out_b  = (const float*)d_in[6];
    const float* enc_ln1_g  = (const float*)d_in[7];
    const float* enc_ln1_b  = (const float*)d_in[8];
    const float* enc_ln2_g  = (const float*)d_in[9];
    const float* enc_ln2_b  = (const float*)d_in[10];
    const float* enc_ff1_w  = (const float*)d_in[11];
    const float* enc_ff1_b  = (const float*)d_in[12];
    const float* enc_ff2_w  = (const float*)d_in[13];
    const float* enc_ff2_b  = (const float*)d_in[14];
    const float* gene_embed = (const float*)d_in[15];
    const float* ca_qkv_w   = (const float*)d_in[16];
    const float* ca_qkv_b   = (const float*)d_in[17];
    const float* ca_out_w   = (const float*)d_in[18];
    const float* ca_out_b   = (const float*)d_in[19];
    const float* ro_ln_g    = (const float*)d_in[20];
    const float* ro_ln_b    = (const float*)d_in[21];
    const float* ro_w       = (const float*)d_in[22];
    const float* ro_b       = (const float*)d_in[23];

    float* pred = (float*)d_out;
    float* z    = pred + (size_t)8 * 2048;

    // workspace carve-up (~79 MB)
    char* wsb = (char*)d_ws;
    char* wp = wsb;
    float* x = (float*)wp;                       wp += (size_t)4096 * 512 * 4;   // 8 MB   [0..8)
    unsigned short* x16   = (unsigned short*)wp; wp += (size_t)4096 * 512 * 2;   // 4 MB   [8..12)
    unsigned short* h16   = (unsigned short*)wp; wp += (size_t)4096 * 512 * 2;   // 4 MB   [12..16)
    unsigned short* qkv16 = (unsigned short*)wp; wp += (size_t)4096 * 1536 * 2;  // 12 MB  [16..28)
    unsigned short* ao16  = (unsigned short*)wp; wp += (size_t)4096 * 512 * 2;   // 4 MB   [28..32)
    unsigned short* big16 = (unsigned short*)wp; wp += (size_t)16384 * 512 * 2;  // 16 MB  [32..48)
    unsigned short* vt16  = (unsigned short*)wp; wp += (size_t)512 * 4096 * 2;   // 4 MB   [48..52)
    unsigned short* wall16 = (unsigned short*)wp;  // all bf16 weights, contiguous in cvt_all order:
    unsigned short* wW16     = wall16;
    unsigned short* wqkv16   = wW16     + (size_t)512 * 1024;
    unsigned short* wout16   = wqkv16   + (size_t)4 * 1536 * 512;
    unsigned short* wff116   = wout16   + (size_t)4 * 512 * 512;
    unsigned short* wff216   = wff116   + (size_t)4 * 2048 * 512;
    unsigned short* wcaqkv16 = wff216   + (size_t)4 * 512 * 2048;
    unsigned short* wcaout16 = wcaqkv16 + (size_t)1536 * 512;
    // aliases (lifetimes disjoint)
    unsigned short* pw16    = big16;                         // 4096x1024 (stage 1)
    unsigned short* ff116   = big16;                         // 4096x2048 (FF, per layer)
    unsigned short* oc16    = big16;                         // 16384x512 (cross output)
    unsigned short* opart16 = big16;                         // self: 4x(4096x512) partials in big16
    float2* mlbuf = (float2*)(qkv16 + (size_t)4096 * 1024);  // qkv16 tail [24..28) MB
    unsigned short* ge16  = qkv16;                           // 2048x512   [16..18) MB
    unsigned short* qg16  = qkv16 + (size_t)2048 * 512;      // 2048x512   [18..20) MB
    unsigned short* kc16  = qkv16 + (size_t)2 * 2048 * 512;  // 4096x512   [20..24) MB

    // weights fp32 -> bf16, single launch
    cvt_all_k<<<13824, 256, 0, stream>>>(W_window, enc_qkv_w, enc_out_w, enc_ff1_w,
                                         enc_ff2_w, ca_qkv_w, ca_out_w, wall16);

    // 1) pool + window projection + posenc -> x (fp32)
    pool_windows_k<<<4096, 256, 0, stream>>>(windows, pw16);
    gemm_bf16_k<false, false, false, false, true, true, false><<<dim3(64, 8), 256, 0, stream>>>(
        pw16, wW16, nullptr, nullptr, x, nullptr, 4096, 512, 1024);

    // 2) encoder layers
    for (int l = 0; l < 4; ++l) {
        const unsigned short* wl = wqkv16 + (size_t)l * 1536 * 512;
        ln_k<<<1024, 256, 0, stream>>>(x, h16, enc_ln1_g + l * 512, enc_ln1_b + l * 512);
        // fused: QK projection (1024 blocks) + V^T (512 blocks)
        gemm_qkv_fused_k<<<1536, 256, 0, stream>>>(
            h16, wl, enc_qkv_b + l * 1536,
            wl + (size_t)1024 * 512, enc_qkv_b + l * 1536 + 1024,
            qkv16, vt16);
        // flash, KV-split x4, XCD-colocated grid -> partials in big16, combine -> ao16
        flashc_k<true><<<dim3(64, 8, 4), 256, 0, stream>>>(
            qkv16, (long long)512 * 1024, 1024,
            qkv16 + 512, (long long)512 * 1024, 1024,
            vt16, (long long)64 * 4096, 512LL, 4096,
            nullptr, 0LL, 0,
            opart16, (long long)4096 * 512, 512, mlbuf, 2);
        combine_k<4, 512><<<4096, 256, 0, stream>>>(opart16, (long long)4096 * 512, mlbuf, ao16);
        gemm_bf16_k<true, false, true, false, false, true, false><<<dim3(64, 8), 256, 0, stream>>>(
            ao16, wout16 + (size_t)l * 512 * 512, enc_out_b + l * 512, x, x, nullptr, 4096, 512, 512);
        ln_k<<<1024, 256, 0, stream>>>(x, h16, enc_ln2_g + l * 512, enc_ln2_b + l * 512);
        gemm_bf16_k<true, false, false, true, false, false, true><<<dim3(64, 32), 256, 0, stream>>>(
            h16, wff116 + (size_t)l * 2048 * 512, enc_ff1_b + l * 2048, nullptr,
            nullptr, ff116, 4096, 2048, 512);
        if (l == 3)
            gemm_bf16_k<true, false, true, false, false, true, true><<<dim3(64, 8), 256, 0, stream>>>(
                ff116, wff216 + (size_t)l * 512 * 2048, enc_ff2_b + l * 512, x, x, x16, 4096, 512, 2048);
        else
            gemm_bf16_k<true, false, true, false, false, true, false><<<dim3(64, 8), 256, 0, stream>>>(
                ff116, wff216 + (size_t)l * 512 * 2048, enc_ff2_b + l * 512, x, x, nullptr, 4096, 512, 2048);
    }

    // 3) cross-attention (fused projections, flash unsplit, XCD-colocated grid)
    gather_k<<<2048, 128, 0, stream>>>(gene_embed, gene_ids, ge16);
    gemm_cross_fused_k<<<1280, 256, 0, stream>>>(
        ge16, x16, wcaqkv16, ca_qkv_b, qg16, kc16, vt16);
    flashc_k<false><<<dim3(64, 32, 1), 256, 0, stream>>>(
        qg16, 0LL, 512,
        kc16, (long long)512 * 512, 512,
        vt16, (long long)64 * 4096, 512LL, 4096,
        oc16, (long long)2048 * 512, 512,
        nullptr, 0LL, 0, nullptr, 8);
    gemm_bf16_k<true, false, false, false, false, true, false><<<dim3(256, 8), 256, 0, stream>>>(
        oc16, wcaout16, ca_out_b, nullptr, z, nullptr, 16384, 512, 512);

    // 4) readout
    readout_k<<<4096, 256, 0, stream>>>(z, ro_ln_g, ro_ln_b, ro_w, ro_b, pred);
}